// Round 1
// baseline (87.730 us; speedup 1.0000x reference)
//
#include <hip/hip_runtime.h>

// ---------------- compile-time constants (constexpr Newton sqrt) ------------
constexpr double csqrt(double x) {
    double r = x > 1.0 ? x : 1.0;
    for (int i = 0; i < 60; ++i) r = 0.5 * (r + x / r);
    return r;
}

constexpr double PI_D    = 3.14159265358979323846264338327950288;
constexpr double SQ2R    = csqrt(0.5);            // sqrt(1/2)
constexpr double SQ2PIR  = csqrt(0.5 / PI_D);     // sqrt(1/(2pi))
constexpr double C00_D   = SQ2PIR * SQ2R;         // Y00
constexpr double C1Y_D   = -csqrt(1.5) * SQ2PIR;  // p1[1]*sqrt(1/(2pi))
constexpr double C1Z_D   = csqrt(3.0) * SQ2R * SQ2PIR;
constexpr double HC1_D   = csqrt(15.0 / (4.0 * PI_D));
constexpr double HC2_D   = csqrt(5.0 / (16.0 * PI_D));
constexpr double HC3_D   = csqrt(15.0 / (16.0 * PI_D));

struct SphConsts {
    double ca[7][7];
    double cb[7][7];
    double p1[7];
    double p2[7];
};

constexpr SphConsts makeConsts() {
    SphConsts c{};
    for (int l = 1; l < 7; ++l) {
        for (int m = 0; m < l; ++m) {
            c.ca[l][m] = csqrt((4.0 * l * l - 1.0) / (double)(l * l - m * m));
            double num = (double)((l - 1) * (l - 1) - m * m);
            double den = 4.0 * (l - 1) * (l - 1) - 1.0;
            // for l==1 this is 0/-1; csqrt(~0) ~ 0, entry unused anyway
            c.cb[l][m] = -csqrt(num / den < 0.0 ? 0.0 : num / den);
        }
        c.p1[l] = -csqrt(1.0 + 0.5 / (double)l);
    }
    for (int l = 0; l < 7; ++l) c.p2[l] = csqrt(2.0 * l + 3.0);
    return c;
}

constexpr SphConsts CC = makeConsts();

// ---------------- tiny 4-wide vector type -----------------------------------
struct alignas(16) F4 { float a, b, c, d; };

__device__ __forceinline__ F4 operator+(F4 u, F4 v) { return {u.a + v.a, u.b + v.b, u.c + v.c, u.d + v.d}; }
__device__ __forceinline__ F4 operator-(F4 u, F4 v) { return {u.a - v.a, u.b - v.b, u.c - v.c, u.d - v.d}; }
__device__ __forceinline__ F4 operator*(F4 u, F4 v) { return {u.a * v.a, u.b * v.b, u.c * v.c, u.d * v.d}; }
__device__ __forceinline__ F4 operator*(float s, F4 v) { return {s * v.a, s * v.b, s * v.c, s * v.d}; }

template <typename T> __device__ __forceinline__ T bcast(float v);
template <> __device__ __forceinline__ float bcast<float>(float v) { return v; }
template <> __device__ __forceinline__ F4    bcast<F4>(float v)    { return {v, v, v, v}; }

template <typename T> __device__ __forceinline__ void stv(float* p, T v);
template <> __device__ __forceinline__ void stv<float>(float* p, float v) { *p = v; }
template <> __device__ __forceinline__ void stv<F4>(float* p, F4 v) { *reinterpret_cast<F4*>(p) = v; }

// ---------------- per-point (or per-4-point) computation --------------------
// o points at out[point_idx]; row k lives at o + k*N.
template <typename T>
__device__ __forceinline__ void sph_point(T X, T Y, T Z, float* __restrict__ o, int N) {
    const T D = X * X + Y * Y + Z * Z;

    // l = 0
    stv<T>(o + 0 * (size_t)N, bcast<T>((float)C00_D));
    // l = 1  (band-local index j = 1 + m)
    T b1_0 = (float)C1Y_D * Y;   // sph[1]
    T b1_1 = (float)C1Z_D * Z;   // sph[2]
    T b1_2 = (float)C1Y_D * X;   // sph[3]
    stv<T>(o + 1 * (size_t)N, b1_0);
    stv<T>(o + 2 * (size_t)N, b1_1);
    stv<T>(o + 3 * (size_t)N, b1_2);
    // l = 2 hard-coded block (band-local j = 2 + m)
    T b2_0 = (float)HC1_D * (X * Y);
    T b2_1 = (float)(-HC1_D) * (Y * Z);
    T b2_2 = (float)HC2_D * ((3.0f * (Z * Z)) - D);
    T b2_3 = (float)(-HC1_D) * (X * Z);
    T b2_4 = (float)HC3_D * (X * X - Y * Y);
    stv<T>(o + 4 * (size_t)N, b2_0);
    stv<T>(o + 5 * (size_t)N, b2_1);
    stv<T>(o + 6 * (size_t)N, b2_2);
    stv<T>(o + 7 * (size_t)N, b2_3);
    stv<T>(o + 8 * (size_t)N, b2_4);

    // streaming recurrence, bands l = 3..6; band-local index j = l + m
    T prev2[13], prev[13], cur[13];
    prev2[0] = b1_0; prev2[1] = b1_1; prev2[2] = b1_2;
    prev[0] = b2_0; prev[1] = b2_1; prev[2] = b2_2; prev[3] = b2_3; prev[4] = b2_4;

#pragma unroll
    for (int l = 3; l <= 6; ++l) {
        // positive-m branch, m = 0..l-2
#pragma unroll
        for (int m = 0; m <= l - 2; ++m) {
            const float a = (float)CC.ca[l][m];
            const float b = (float)CC.cb[l][m];
            cur[l + m] = a * (Z * prev[(l - 1) + m] + b * (D * prev2[(l - 2) + m]));
        }
        // negative-m branch, m = 1..l-2
#pragma unroll
        for (int m = 1; m <= l - 2; ++m) {
            const float a = (float)CC.ca[l][m];
            const float b = (float)CC.cb[l][m];
            cur[l - m] = a * (Z * prev[(l - 1) - m] + b * (D * prev2[(l - 2) - m]));
        }
        // edge terms
        const T top_p = prev[2 * l - 2];
        const T top_n = prev[0];
        const float p2v = (float)CC.p2[l - 1];
        const float p1v = (float)CC.p1[l];
        cur[2 * l - 1] = p2v * (Z * top_p);
        cur[1]         = p2v * (Z * top_n);
        cur[2 * l]     = p1v * ((X * top_p) - (Y * top_n));
        cur[0]         = p1v * ((X * top_n) + (Y * top_p));

        // store band l: global row l*l + j
#pragma unroll
        for (int j = 0; j <= 2 * l; ++j)
            stv<T>(o + (size_t)(l * l + j) * (size_t)N, cur[j]);

        // shift bands
#pragma unroll
        for (int j = 0; j < 2 * l - 1; ++j) prev2[j] = prev[j];
#pragma unroll
        for (int j = 0; j < 2 * l + 1; ++j) prev[j] = cur[j];
    }
}

// ---------------- kernels ---------------------------------------------------
__global__ void sph_vec_kernel(const float* __restrict__ cart, float* __restrict__ out, int N) {
    const int n4 = N >> 2;
    const int i = blockIdx.x * blockDim.x + threadIdx.x;
    if (i >= n4) return;
    const float* p = cart + 4 * (size_t)i;
    F4 X = *reinterpret_cast<const F4*>(p);
    F4 Y = *reinterpret_cast<const F4*>(p + (size_t)N);
    F4 Z = *reinterpret_cast<const F4*>(p + 2 * (size_t)N);
    sph_point<F4>(X, Y, Z, out + 4 * (size_t)i, N);
}

__global__ void sph_scalar_kernel(const float* __restrict__ cart, float* __restrict__ out, int N) {
    const int i = blockIdx.x * blockDim.x + threadIdx.x;
    if (i >= N) return;
    sph_point<float>(cart[i], cart[(size_t)N + i], cart[2 * (size_t)N + i], out + i, N);
}

// ---------------- launch ----------------------------------------------------
extern "C" void kernel_launch(void* const* d_in, const int* in_sizes, int n_in,
                              void* d_out, int out_size, void* d_ws, size_t ws_size,
                              hipStream_t stream) {
    const float* cart = (const float*)d_in[0];
    float* out = (float*)d_out;
    const int N = in_sizes[0] / 3;

    const int threads = 256;
    if ((N & 3) == 0) {
        const int n4 = N >> 2;
        const int blocks = (n4 + threads - 1) / threads;
        sph_vec_kernel<<<blocks, threads, 0, stream>>>(cart, out, N);
    } else {
        const int blocks = (N + threads - 1) / threads;
        sph_scalar_kernel<<<blocks, threads, 0, stream>>>(cart, out, N);
    }
}

// Round 2
// 78.990 us; speedup vs baseline: 1.1107x; 1.1107x over previous
//
#include <hip/hip_runtime.h>

// ---------------- compile-time constants (constexpr Newton sqrt) ------------
constexpr double csqrt(double x) {
    double r = x > 1.0 ? x : 1.0;
    for (int i = 0; i < 60; ++i) r = 0.5 * (r + x / r);
    return r;
}

constexpr double PI_D    = 3.14159265358979323846264338327950288;
constexpr double SQ2R    = csqrt(0.5);            // sqrt(1/2)
constexpr double SQ2PIR  = csqrt(0.5 / PI_D);     // sqrt(1/(2pi))
constexpr double C00_D   = SQ2PIR * SQ2R;         // Y00
constexpr double C1Y_D   = -csqrt(1.5) * SQ2PIR;  // p1[1]*sqrt(1/(2pi))
constexpr double C1Z_D   = csqrt(3.0) * SQ2R * SQ2PIR;
constexpr double HC1_D   = csqrt(15.0 / (4.0 * PI_D));
constexpr double HC2_D   = csqrt(5.0 / (16.0 * PI_D));
constexpr double HC3_D   = csqrt(15.0 / (16.0 * PI_D));

struct SphConsts {
    double ca[7][7];
    double cb[7][7];
    double p1[7];
    double p2[7];
};

constexpr SphConsts makeConsts() {
    SphConsts c{};
    for (int l = 1; l < 7; ++l) {
        for (int m = 0; m < l; ++m) {
            c.ca[l][m] = csqrt((4.0 * l * l - 1.0) / (double)(l * l - m * m));
            double num = (double)((l - 1) * (l - 1) - m * m);
            double den = 4.0 * (l - 1) * (l - 1) - 1.0;
            c.cb[l][m] = -csqrt(num / den < 0.0 ? 0.0 : num / den);
        }
        c.p1[l] = -csqrt(1.0 + 0.5 / (double)l);
    }
    for (int l = 0; l < 7; ++l) c.p2[l] = csqrt(2.0 * l + 3.0);
    return c;
}

constexpr SphConsts CC = makeConsts();

// ---------------- per-point computation, scalar, NT stores ------------------
// o points at out[point_idx]; row k lives at o + k*N.
__device__ __forceinline__ void sph_point(float X, float Y, float Z,
                                          float* __restrict__ o, size_t N) {
    const float D = X * X + Y * Y + Z * Z;

    // l = 0
    __builtin_nontemporal_store((float)C00_D, o);
    // l = 1  (band-local index j = 1 + m)
    float b1_0 = (float)C1Y_D * Y;   // sph[1]
    float b1_1 = (float)C1Z_D * Z;   // sph[2]
    float b1_2 = (float)C1Y_D * X;   // sph[3]
    __builtin_nontemporal_store(b1_0, o + 1 * N);
    __builtin_nontemporal_store(b1_1, o + 2 * N);
    __builtin_nontemporal_store(b1_2, o + 3 * N);
    // l = 2 hard-coded block (band-local j = 2 + m)
    float b2_0 = (float)HC1_D * (X * Y);
    float b2_1 = (float)(-HC1_D) * (Y * Z);
    float b2_2 = (float)HC2_D * (3.0f * (Z * Z) - D);
    float b2_3 = (float)(-HC1_D) * (X * Z);
    float b2_4 = (float)HC3_D * (X * X - Y * Y);
    __builtin_nontemporal_store(b2_0, o + 4 * N);
    __builtin_nontemporal_store(b2_1, o + 5 * N);
    __builtin_nontemporal_store(b2_2, o + 6 * N);
    __builtin_nontemporal_store(b2_3, o + 7 * N);
    __builtin_nontemporal_store(b2_4, o + 8 * N);

    // streaming recurrence, bands l = 3..6; band-local index j = l + m
    float prev2[13], prev[13], cur[13];
    prev2[0] = b1_0; prev2[1] = b1_1; prev2[2] = b1_2;
    prev[0] = b2_0; prev[1] = b2_1; prev[2] = b2_2; prev[3] = b2_3; prev[4] = b2_4;

#pragma unroll
    for (int l = 3; l <= 6; ++l) {
        // positive-m branch, m = 0..l-2
#pragma unroll
        for (int m = 0; m <= l - 2; ++m) {
            const float a = (float)CC.ca[l][m];
            const float b = (float)CC.cb[l][m];
            cur[l + m] = a * (Z * prev[(l - 1) + m] + b * (D * prev2[(l - 2) + m]));
        }
        // negative-m branch, m = 1..l-2
#pragma unroll
        for (int m = 1; m <= l - 2; ++m) {
            const float a = (float)CC.ca[l][m];
            const float b = (float)CC.cb[l][m];
            cur[l - m] = a * (Z * prev[(l - 1) - m] + b * (D * prev2[(l - 2) - m]));
        }
        // edge terms
        const float top_p = prev[2 * l - 2];
        const float top_n = prev[0];
        const float p2v = (float)CC.p2[l - 1];
        const float p1v = (float)CC.p1[l];
        cur[2 * l - 1] = p2v * (Z * top_p);
        cur[1]         = p2v * (Z * top_n);
        cur[2 * l]     = p1v * (X * top_p - Y * top_n);
        cur[0]         = p1v * (X * top_n + Y * top_p);

        // store band l: global row l*l + j
#pragma unroll
        for (int j = 0; j <= 2 * l; ++j)
            __builtin_nontemporal_store(cur[j], o + (size_t)(l * l + j) * N);

        // shift bands
#pragma unroll
        for (int j = 0; j < 2 * l - 1; ++j) prev2[j] = prev[j];
#pragma unroll
        for (int j = 0; j < 2 * l + 1; ++j) prev[j] = cur[j];
    }
}

// ---------------- kernel ----------------------------------------------------
__global__ void sph_scalar_kernel(const float* __restrict__ cart,
                                  float* __restrict__ out, int N) {
    const int i = blockIdx.x * blockDim.x + threadIdx.x;
    if (i >= N) return;
    const size_t sN = (size_t)N;
    sph_point(cart[i], cart[sN + i], cart[2 * sN + i], out + i, sN);
}

// ---------------- launch ----------------------------------------------------
extern "C" void kernel_launch(void* const* d_in, const int* in_sizes, int n_in,
                              void* d_out, int out_size, void* d_ws, size_t ws_size,
                              hipStream_t stream) {
    const float* cart = (const float*)d_in[0];
    float* out = (float*)d_out;
    const int N = in_sizes[0] / 3;

    const int threads = 256;
    const int blocks = (N + threads - 1) / threads;
    sph_scalar_kernel<<<blocks, threads, 0, stream>>>(cart, out, N);
}

// Round 3
// 77.511 us; speedup vs baseline: 1.1318x; 1.0191x over previous
//
#include <hip/hip_runtime.h>

// ---------------- compile-time constants (constexpr Newton sqrt) ------------
constexpr double csqrt(double x) {
    double r = x > 1.0 ? x : 1.0;
    for (int i = 0; i < 60; ++i) r = 0.5 * (r + x / r);
    return r;
}

constexpr double PI_D    = 3.14159265358979323846264338327950288;
constexpr double SQ2R    = csqrt(0.5);            // sqrt(1/2)
constexpr double SQ2PIR  = csqrt(0.5 / PI_D);     // sqrt(1/(2pi))
constexpr double C00_D   = SQ2PIR * SQ2R;         // Y00
constexpr double C1Y_D   = -csqrt(1.5) * SQ2PIR;  // p1[1]*sqrt(1/(2pi))
constexpr double C1Z_D   = csqrt(3.0) * SQ2R * SQ2PIR;
constexpr double HC1_D   = csqrt(15.0 / (4.0 * PI_D));
constexpr double HC2_D   = csqrt(5.0 / (16.0 * PI_D));
constexpr double HC3_D   = csqrt(15.0 / (16.0 * PI_D));

struct SphConsts {
    double ca[7][7];
    double cb[7][7];
    double p1[7];
    double p2[7];
};

constexpr SphConsts makeConsts() {
    SphConsts c{};
    for (int l = 1; l < 7; ++l) {
        for (int m = 0; m < l; ++m) {
            c.ca[l][m] = csqrt((4.0 * l * l - 1.0) / (double)(l * l - m * m));
            double num = (double)((l - 1) * (l - 1) - m * m);
            double den = 4.0 * (l - 1) * (l - 1) - 1.0;
            c.cb[l][m] = -csqrt(num / den < 0.0 ? 0.0 : num / den);
        }
        c.p1[l] = -csqrt(1.0 + 0.5 / (double)l);
    }
    for (int l = 0; l < 7; ++l) c.p2[l] = csqrt(2.0 * l + 3.0);
    return c;
}

constexpr SphConsts CC = makeConsts();

// ---------------- vector type + helpers -------------------------------------
typedef float f2 __attribute__((ext_vector_type(2)));

__device__ __forceinline__ void stv(float* p, float v) {
    __builtin_nontemporal_store(v, p);
}
__device__ __forceinline__ void stv(float* p, f2 v) {
    __builtin_nontemporal_store(v, reinterpret_cast<f2*>(p));
}

template <typename T> __device__ __forceinline__ T bcast(float v);
template <> __device__ __forceinline__ float bcast<float>(float v) { return v; }
template <> __device__ __forceinline__ f2    bcast<f2>(float v)    { f2 t = {v, v}; return t; }

// ---------------- per-point computation -------------------------------------
// o points at out[point_idx]; row k lives at o + k*N.
template <typename T>
__device__ __forceinline__ void sph_point(T X, T Y, T Z, float* __restrict__ o, size_t N) {
    const T D = X * X + Y * Y + Z * Z;

    // l = 0
    stv(o, bcast<T>((float)C00_D));
    // l = 1  (band-local index j = 1 + m)
    T b1_0 = (float)C1Y_D * Y;   // sph[1]
    T b1_1 = (float)C1Z_D * Z;   // sph[2]
    T b1_2 = (float)C1Y_D * X;   // sph[3]
    stv(o + 1 * N, b1_0);
    stv(o + 2 * N, b1_1);
    stv(o + 3 * N, b1_2);
    // l = 2 hard-coded block (band-local j = 2 + m)
    T b2_0 = (float)HC1_D * (X * Y);
    T b2_1 = (float)(-HC1_D) * (Y * Z);
    T b2_2 = (float)HC2_D * (3.0f * (Z * Z) - D);
    T b2_3 = (float)(-HC1_D) * (X * Z);
    T b2_4 = (float)HC3_D * (X * X - Y * Y);
    stv(o + 4 * N, b2_0);
    stv(o + 5 * N, b2_1);
    stv(o + 6 * N, b2_2);
    stv(o + 7 * N, b2_3);
    stv(o + 8 * N, b2_4);

    // streaming recurrence, bands l = 3..6; band-local index j = l + m
    T prev2[13], prev[13], cur[13];
    prev2[0] = b1_0; prev2[1] = b1_1; prev2[2] = b1_2;
    prev[0] = b2_0; prev[1] = b2_1; prev[2] = b2_2; prev[3] = b2_3; prev[4] = b2_4;

#pragma unroll
    for (int l = 3; l <= 6; ++l) {
        // positive-m branch, m = 0..l-2
#pragma unroll
        for (int m = 0; m <= l - 2; ++m) {
            const float a = (float)CC.ca[l][m];
            const float b = (float)CC.cb[l][m];
            cur[l + m] = a * (Z * prev[(l - 1) + m] + b * (D * prev2[(l - 2) + m]));
        }
        // negative-m branch, m = 1..l-2
#pragma unroll
        for (int m = 1; m <= l - 2; ++m) {
            const float a = (float)CC.ca[l][m];
            const float b = (float)CC.cb[l][m];
            cur[l - m] = a * (Z * prev[(l - 1) - m] + b * (D * prev2[(l - 2) - m]));
        }
        // edge terms
        const T top_p = prev[2 * l - 2];
        const T top_n = prev[0];
        const float p2v = (float)CC.p2[l - 1];
        const float p1v = (float)CC.p1[l];
        cur[2 * l - 1] = p2v * (Z * top_p);
        cur[1]         = p2v * (Z * top_n);
        cur[2 * l]     = p1v * (X * top_p - Y * top_n);
        cur[0]         = p1v * (X * top_n + Y * top_p);

        // store band l: global row l*l + j
#pragma unroll
        for (int j = 0; j <= 2 * l; ++j)
            stv(o + (size_t)(l * l + j) * N, cur[j]);

        // shift bands
#pragma unroll
        for (int j = 0; j < 2 * l - 1; ++j) prev2[j] = prev[j];
#pragma unroll
        for (int j = 0; j < 2 * l + 1; ++j) prev[j] = cur[j];
    }
}

// ---------------- kernels ---------------------------------------------------
template <typename T, int W>
__global__ void sph_kernel(const float* __restrict__ cart,
                           float* __restrict__ out, int N) {
    const int i = blockIdx.x * blockDim.x + threadIdx.x;   // group of W points
    const int nW = N / W;
    if (i >= nW) return;
    const size_t sN = (size_t)N;
    const float* p = cart + (size_t)W * i;
    T X = *reinterpret_cast<const T*>(p);
    T Y = *reinterpret_cast<const T*>(p + sN);
    T Z = *reinterpret_cast<const T*>(p + 2 * sN);
    sph_point<T>(X, Y, Z, out + (size_t)W * i, sN);
}

// ---------------- launch ----------------------------------------------------
extern "C" void kernel_launch(void* const* d_in, const int* in_sizes, int n_in,
                              void* d_out, int out_size, void* d_ws, size_t ws_size,
                              hipStream_t stream) {
    const float* cart = (const float*)d_in[0];
    float* out = (float*)d_out;
    const int N = in_sizes[0] / 3;

    const int threads = 256;
    if ((N & 1) == 0) {
        const int n2 = N >> 1;
        const int blocks = (n2 + threads - 1) / threads;
        sph_kernel<f2, 2><<<blocks, threads, 0, stream>>>(cart, out, N);
    } else {
        const int blocks = (N + threads - 1) / threads;
        sph_kernel<float, 1><<<blocks, threads, 0, stream>>>(cart, out, N);
    }
}

// Round 4
// 75.886 us; speedup vs baseline: 1.1561x; 1.0214x over previous
//
#include <hip/hip_runtime.h>

// ---------------- compile-time constants (constexpr Newton sqrt) ------------
constexpr double csqrt(double x) {
    double r = x > 1.0 ? x : 1.0;
    for (int i = 0; i < 60; ++i) r = 0.5 * (r + x / r);
    return r;
}

constexpr double PI_D    = 3.14159265358979323846264338327950288;
constexpr double SQ2R    = csqrt(0.5);            // sqrt(1/2)
constexpr double SQ2PIR  = csqrt(0.5 / PI_D);     // sqrt(1/(2pi))
constexpr double C00_D   = SQ2PIR * SQ2R;         // Y00
constexpr double C1Y_D   = -csqrt(1.5) * SQ2PIR;  // p1[1]*sqrt(1/(2pi))

struct SphConsts {
    double ca[7][7];   // a(l,m) = sqrt((4l^2-1)/(l^2-m^2)),   l>=2, m<=l-2
    double cb[7][7];   // b(l,m) = -sqrt(((l-1)^2-m^2)/(4(l-1)^2-1))
    double p1[7];      // -sqrt(1 + 1/(2l))
    double p2[7];      // sqrt(2l+3)
};

constexpr SphConsts makeConsts() {
    SphConsts c{};
    for (int l = 1; l < 7; ++l) {
        for (int m = 0; m < l; ++m) {
            c.ca[l][m] = csqrt((4.0 * l * l - 1.0) / (double)(l * l - m * m));
            double num = (double)((l - 1) * (l - 1) - m * m);
            double den = 4.0 * (l - 1) * (l - 1) - 1.0;
            c.cb[l][m] = -csqrt(num / den < 0.0 ? 0.0 : num / den);
        }
        c.p1[l] = -csqrt(1.0 + 0.5 / (double)l);
    }
    for (int l = 0; l < 7; ++l) c.p2[l] = csqrt(2.0 * l + 3.0);
    return c;
}

constexpr SphConsts CC = makeConsts();

// ---------------- vector types + helpers ------------------------------------
typedef float f4 __attribute__((ext_vector_type(4)));

__device__ __forceinline__ void stv(float* p, float v) {
    __builtin_nontemporal_store(v, p);
}
__device__ __forceinline__ void stv(float* p, f4 v) {
    __builtin_nontemporal_store(v, reinterpret_cast<f4*>(p));
}

template <typename T> __device__ __forceinline__ T bcast(float v);
template <> __device__ __forceinline__ float bcast<float>(float v) { return v; }
template <> __device__ __forceinline__ f4    bcast<f4>(float v)    { f4 t = {v, v, v, v}; return t; }

// ---------------- per-point computation, column-major (m-major) -------------
// o points at out[point_idx]; row k lives at o + k*N.
// Column recurrence: sph[l,m] = a(l,m)*(z*sph[l-1,m] + b(l,m)*d2*sph[l-2,m])
// Diagonal chain:    dp_m = p1[m]*(x*dp_{m-1} - y*dn_{m-1}),
//                    dn_m = p1[m]*(x*dn_{m-1} + y*dp_{m-1})   (seeded at m=1)
// First off-diag:    sph[m+1, m] = p2[m]*z*diag
// Row ids: yr[l,m] = l*l+l+m, yrr[l,m] = l*l+l-m.
template <typename T>
__device__ __forceinline__ void sph_point(T x, T y, T z, float* __restrict__ o, size_t N) {
    const T d2 = x * x + y * y + z * z;

    // ---- m = 0 column (rows l*l+l, l=0..6) ----
    T pa = bcast<T>((float)C00_D);          // l = 0
    stv(o + 0 * N, pa);
    T pb = (float)CC.p2[0] * (z * pa);      // l = 1
    stv(o + 2 * N, pb);
#pragma unroll
    for (int l = 2; l <= 6; ++l) {
        const float a = (float)CC.ca[l][0];
        const float b = (float)CC.cb[l][0];
        T pc = a * (z * pb + b * (d2 * pa));
        stv(o + (size_t)(l * l + l) * N, pc);
        pa = pb; pb = pc;
    }

    // ---- diagonal seeds at l = 1 ----
    T dp = (float)C1Y_D * x;                // sph[3] = yr[1,1]
    T dn = (float)C1Y_D * y;                // sph[1] = yrr[1,1]
    stv(o + 3 * N, dp);
    stv(o + 1 * N, dn);

    // ---- columns m = 1..6 ----
#pragma unroll
    for (int m = 1; m <= 6; ++m) {
        if (m >= 2) {
            // advance the diagonal to (m,m)
            const float p1v = (float)CC.p1[m];
            T ndp = p1v * (x * dp - y * dn);
            T ndn = p1v * (x * dn + y * dp);
            dp = ndp; dn = ndn;
            stv(o + (size_t)(m * m + 2 * m) * N, dp);   // yr[m,m]
            stv(o + (size_t)(m * m) * N, dn);           // yrr[m,m]
        }
        if (m <= 5) {
            // first off-diagonal: l = m+1
            const float p2v = (float)CC.p2[m];
            T qp = p2v * (z * dp);
            T qn = p2v * (z * dn);
            {
                const int l = m + 1;
                stv(o + (size_t)(l * l + l + m) * N, qp);
                stv(o + (size_t)(l * l + l - m) * N, qn);
            }
            // column walk l = m+2 .. 6
            T ap = dp, bp = qp, an = dn, bn = qn;
#pragma unroll
            for (int l = m + 2; l <= 6; ++l) {
                const float a = (float)CC.ca[l][m];
                const float b = (float)CC.cb[l][m];
                T cp = a * (z * bp + b * (d2 * ap));
                T cn = a * (z * bn + b * (d2 * an));
                stv(o + (size_t)(l * l + l + m) * N, cp);
                stv(o + (size_t)(l * l + l - m) * N, cn);
                ap = bp; bp = cp;
                an = bn; bn = cn;
            }
        }
    }
}

// ---------------- kernels ---------------------------------------------------
template <typename T, int W>
__global__ void sph_kernel(const float* __restrict__ cart,
                           float* __restrict__ out, int N) {
    const int i = blockIdx.x * blockDim.x + threadIdx.x;   // group of W points
    const int nW = N / W;
    if (i >= nW) return;
    const size_t sN = (size_t)N;
    const float* p = cart + (size_t)W * i;
    T X = *reinterpret_cast<const T*>(p);
    T Y = *reinterpret_cast<const T*>(p + sN);
    T Z = *reinterpret_cast<const T*>(p + 2 * sN);
    sph_point<T>(X, Y, Z, out + (size_t)W * i, sN);
}

// ---------------- launch ----------------------------------------------------
extern "C" void kernel_launch(void* const* d_in, const int* in_sizes, int n_in,
                              void* d_out, int out_size, void* d_ws, size_t ws_size,
                              hipStream_t stream) {
    const float* cart = (const float*)d_in[0];
    float* out = (float*)d_out;
    const int N = in_sizes[0] / 3;

    const int threads = 256;
    if ((N & 3) == 0) {
        const int n4 = N >> 2;
        const int blocks = (n4 + threads - 1) / threads;
        sph_kernel<f4, 4><<<blocks, threads, 0, stream>>>(cart, out, N);
    } else {
        const int blocks = (N + threads - 1) / threads;
        sph_kernel<float, 1><<<blocks, threads, 0, stream>>>(cart, out, N);
    }
}